// Round 6
// baseline (950.454 us; speedup 1.0000x reference)
//
#include <hip/hip_runtime.h>
#include <hip/hip_bf16.h>

typedef __hip_bfloat16 bf16;
using bf16x8 = __attribute__((ext_vector_type(8))) short;
using f32x4  = __attribute__((ext_vector_type(4))) float;

#define S_LEN 1024
#define CDIM  576
#define NHEAD 8
#define DKH   72
#define BATCH 4
#define MROWS 4096   // B*S
#define FFDIM 2304
#define QKVN  1728   // 3*C, real
#define QKVNP 1792   // padded to x128
#define CPAD  640    // C padded to x128

// async global->LDS, 16B per lane, lane-ordered LDS destination
__device__ __forceinline__ void gload16(const void* g, void* l) {
  __builtin_amdgcn_global_load_lds(
      (const __attribute__((address_space(1))) unsigned int*)g,
      (__attribute__((address_space(3))) unsigned int*)l, 16, 0, 0);
}

// float -> bf16 bits (RNE), pure integer math (type-safe for LDS punning)
__device__ __forceinline__ short f2bf_bits(float x) {
  unsigned int u = __float_as_uint(x);
  u += 0x7fffu + ((u >> 16) & 1u);
  return (short)(u >> 16);
}

// ---------------- weight transpose + fp32->bf16 convert ----------------
// in: per-layer [K,N] fp32 (layer stride in_ls) -> out: [N,K] bf16 (layer stride out_ls)
__global__ __launch_bounds__(256) void transpose_cvt(
    const float* __restrict__ in, bf16* __restrict__ out, int K, int N,
    size_t in_ls, size_t out_ls) {
  __shared__ float tile[32][33];
  const float* inl = in + (size_t)blockIdx.z * in_ls;
  bf16* outl = out + (size_t)blockIdx.z * out_ls;
  int n0 = blockIdx.x * 32, k0 = blockIdx.y * 32;
  int tx = threadIdx.x & 31, ty = threadIdx.x >> 5;   // ty 0..7
#pragma unroll
  for (int i = 0; i < 32; i += 8)
    tile[ty + i][tx] = inl[(size_t)(k0 + ty + i) * N + (n0 + tx)];
  __syncthreads();
#pragma unroll
  for (int i = 0; i < 32; i += 8)
    outl[(size_t)(n0 + ty + i) * K + (k0 + tx)] = __float2bfloat16(tile[tx][ty + i]);
}

// ---------------- xf = right_shift(x) + pos ----------------
__global__ __launch_bounds__(256) void build_xf(
    const float* __restrict__ x, const float* __restrict__ p0,
    const float* __restrict__ p1, const float* __restrict__ p2,
    float* __restrict__ xf) {
  int idx = blockIdx.x * 256 + threadIdx.x;      // one float4 per thread
  int c4 = idx % 144;
  int s  = (idx / 144) & (S_LEN - 1);
  int b  = idx / (144 * S_LEN);
  int c  = c4 * 4;
  int t = s >> 8, hh = (s >> 4) & 15, w = s & 15;
  float4 pv;
  if (c < 192)       pv = *(const float4*)&p0[t  * 192 + c];
  else if (c < 384)  pv = *(const float4*)&p1[hh * 192 + c - 192];
  else               pv = *(const float4*)&p2[w  * 192 + c - 384];
  float4 xv = make_float4(0.f, 0.f, 0.f, 0.f);
  if (s > 0) xv = *(const float4*)&x[((size_t)b * S_LEN + s - 1) * CDIM + c];
  float4 r = make_float4(xv.x + pv.x, xv.y + pv.y, xv.z + pv.z, xv.w + pv.w);
  *(float4*)&xf[((size_t)b * S_LEN + s) * CDIM + c] = r;
}

// ---------------- LayerNorm (eps added to rsqrt, per reference) ----------------
__global__ __launch_bounds__(256) void ln_kernel(
    const float* __restrict__ x, const float* __restrict__ g,
    const float* __restrict__ b, bf16* __restrict__ out) {
  int row  = blockIdx.x * 4 + (threadIdx.x >> 6);
  int lane = threadIdx.x & 63;
  const float* xr = x + (size_t)row * CDIM;
  float vals[9];
  float sum = 0.f;
#pragma unroll
  for (int i = 0; i < 9; i++) { vals[i] = xr[lane + 64 * i]; sum += vals[i]; }
#pragma unroll
  for (int o = 1; o < 64; o <<= 1) sum += __shfl_xor(sum, o);
  float mu = sum * (1.f / CDIM);
  float vs = 0.f;
#pragma unroll
  for (int i = 0; i < 9; i++) { float d = vals[i] - mu; vs += d * d; }
#pragma unroll
  for (int o = 1; o < 64; o <<= 1) vs += __shfl_xor(vs, o);
  float mult = 1e-5f + rsqrtf(vs * (1.f / CDIM));
  bf16* orow = out + (size_t)row * CDIM;
#pragma unroll
  for (int i = 0; i < 9; i++) {
    int c = lane + 64 * i;
    orow[c] = __float2bfloat16((vals[i] - mu) * mult * g[c] + b[c]);
  }
}

// ---------------- GEMM v2: fragment-linear LDS via global_load_lds ----------------
// out[M, Nreal] = act(A[M,K] @ Bt[Npad,K]^T + bias) (+ res)
// BM=64, BK=64, BN in {64,128}. grid (M/64, Npad/BN), 256 threads (4 waves 2x2).
// LDS strips: 16 rows x 32 k x bf16 = 1024B, stored in the exact lane order the
// MFMA fragment read wants -> ds_read_b128 fully sequential, conflict-free.
template <int BN, bool BIAS, bool RES, int ACT, bool OUTBF>
__global__ __launch_bounds__(256) void gemm2(
    const bf16* __restrict__ A, const bf16* __restrict__ Bt,
    const float* __restrict__ bias, const float* __restrict__ res,
    void* __restrict__ outp, int Nreal, int ostride, int K) {
  constexpr int NI = BN / 32;              // n-frags per wave
  constexpr int BSTR = BN / 16;            // B strips per k-page
  __shared__ short ldsA[2 * 4 * 512];      // [kc][strip][512]
  __shared__ short ldsB[2 * BSTR * 512];
  const int tid = threadIdx.x, lane = tid & 63, wave = tid >> 6;
  const int lr = lane & 15, quad = lane >> 4;
  const int m0 = blockIdx.x * 64, n0 = blockIdx.y * BN;
  const int wm = (wave & 1) * 32, wn = (wave >> 1) * (BN / 2);
  f32x4 acc[2][NI] = {};
  const short* Ag  = (const short*)A  + (size_t)(m0 + wave * 16 + lr) * K + quad * 8;
  const short* Bg0 = (const short*)Bt + (size_t)(n0 + wave * 16 + lr) * K + quad * 8;
  const short* Bg1 = (const short*)Bt + (size_t)(n0 + (wave + 4) * 16 + lr) * K + quad * 8;

  for (int k0 = 0; k0 < K; k0 += 64) {
    __syncthreads();                       // all waves done reading prev tiles
#pragma unroll
    for (int kc = 0; kc < 2; kc++) {
      gload16(Ag + k0 + kc * 32, &ldsA[(kc * 4 + wave) * 512]);
      gload16(Bg0 + k0 + kc * 32, &ldsB[(kc * BSTR + wave) * 512]);
      if (BN == 128) gload16(Bg1 + k0 + kc * 32, &ldsB[(kc * BSTR + wave + 4) * 512]);
    }
    __syncthreads();                       // drains vmcnt -> LDS valid
#pragma unroll
    for (int kc = 0; kc < 2; kc++) {
      bf16x8 af[2], bfv[NI];
#pragma unroll
      for (int mi = 0; mi < 2; mi++)
        af[mi] = *(const bf16x8*)&ldsA[(kc * 4 + (wave & 1) * 2 + mi) * 512 + lane * 8];
#pragma unroll
      for (int ni = 0; ni < NI; ni++)
        bfv[ni] = *(const bf16x8*)&ldsB[(kc * BSTR + (wave >> 1) * NI + ni) * 512 + lane * 8];
#pragma unroll
      for (int mi = 0; mi < 2; mi++)
#pragma unroll
        for (int ni = 0; ni < NI; ni++)
          acc[mi][ni] = __builtin_amdgcn_mfma_f32_16x16x32_bf16(af[mi], bfv[ni], acc[mi][ni], 0, 0, 0);
    }
  }

  float* fout = (float*)outp;
  bf16*  bout = (bf16*)outp;
#pragma unroll
  for (int mi = 0; mi < 2; mi++)
#pragma unroll
    for (int ni = 0; ni < NI; ni++) {
      int col = n0 + wn + ni * 16 + lr;
      if (col < Nreal) {
#pragma unroll
        for (int r = 0; r < 4; r++) {
          int row = m0 + wm + mi * 16 + quad * 4 + r;
          float v = acc[mi][ni][r];
          if (BIAS) v += bias[col];
          if (ACT == 1) v = v / (1.f + __expf(-1.702f * v));   // GeLU2
          size_t idx = (size_t)row * ostride + col;
          if (RES) v += res[idx];
          if (OUTBF) bout[idx] = __float2bfloat16(v);
          else       fout[idx] = v;
        }
      }
    }
}

// ---------------- MFMA flash attention v2 ----------------
// grid (16, B*NH): one 64-row q-tile per block (qt = 15-bx, heavy first), 512 blocks.
// qkv: bf16 [B*S][1728]; K staged fragment-linear via global_load_lds; V^T manual.
__global__ __launch_bounds__(256) void attn_mfma(
    const bf16* __restrict__ qkv, bf16* __restrict__ a) {
  __shared__ short ldsK[12 * 512];     // page (nc*3+c), lane-linear
  __shared__ short ldsVt[80][104];     // [d][key], padded rows (52 dw -> ~2-way)
  __shared__ short ldsP[4 * 1024];     // per-wave, fragment-linear (2 kc pages)
  const int bh = blockIdx.y, b = bh >> 3, h = bh & 7;
  const int tid = threadIdx.x, wave = tid >> 6, lane = tid & 63;
  const int lr = lane & 15, quad = lane >> 4;
  const int qt = 15 - (int)blockIdx.x;
  const float scale = 0.11785113019775793f;  // 1/sqrt(72)
  const int qcol = h * DKH, kcol = CDIM + h * DKH, vcol = 2 * CDIM + h * DKH;

  const int qrow = qt * 64 + wave * 16 + lr;
  const short* qg = (const short*)qkv + (size_t)(b * S_LEN + qrow) * QKVN + qcol;
  bf16x8 qfrag[3];
#pragma unroll
  for (int c = 0; c < 3; c++) {
    int d0 = c * 32 + quad * 8;
    bf16x8 z = {0, 0, 0, 0, 0, 0, 0, 0};
    qfrag[c] = (d0 < DKH) ? *(const bf16x8*)(qg + d0) : z;
  }
  f32x4 oacc[5] = {};
  float m[4], l[4];
#pragma unroll
  for (int r = 0; r < 4; r++) { m[r] = -1e30f; l[r] = 0.f; }

  for (int kt = 0; kt <= qt; kt++) {
    __syncthreads();
    // ---- K pages async: wave w stages keys nc=w, 3 d-pages ----
    {
      const short* kg = (const short*)qkv +
          (size_t)(b * S_LEN + kt * 64 + wave * 16 + lr) * QKVN + kcol + quad * 8;
#pragma unroll
      for (int c = 0; c < 3; c++)
        gload16(kg + c * 32, &ldsK[(wave * 3 + c) * 512]);
    }
    // ---- V^T manual (transpose scatter; conflict-free b16 writes) ----
    {
      int key = tid & 63, dgb = tid >> 6;
      const short* vg = (const short*)qkv + (size_t)(b * S_LEN + kt * 64 + key) * QKVN + vcol;
#pragma unroll
      for (int pass = 0; pass < 3; pass++) {
        int d0 = (dgb + pass * 4) * 8;  // 0..88
        if (d0 < 80) {
          bf16x8 vv = {0, 0, 0, 0, 0, 0, 0, 0};
          if (d0 < DKH) vv = *(const bf16x8*)(vg + d0);
#pragma unroll
          for (int j = 0; j < 8; j++) ldsVt[d0 + j][key] = vv[j];
        }
      }
    }
    __syncthreads();
    // ---- S = Q K^T (frag reads conflict-free) ----
    f32x4 sacc[4] = {};
#pragma unroll
    for (int nc = 0; nc < 4; nc++)
#pragma unroll
      for (int c = 0; c < 3; c++) {
        bf16x8 kf = *(const bf16x8*)&ldsK[(nc * 3 + c) * 512 + lane * 8];
        sacc[nc] = __builtin_amdgcn_mfma_f32_16x16x32_bf16(qfrag[c], kf, sacc[nc], 0, 0, 0);
      }
    // ---- scale + causal mask + online softmax ----
    float tmax[4];
#pragma unroll
    for (int r = 0; r < 4; r++) tmax[r] = -1e30f;
    bool diag = (kt == qt);
#pragma unroll
    for (int nc = 0; nc < 4; nc++)
#pragma unroll
      for (int r = 0; r < 4; r++) {
        float s = sacc[nc][r] * scale;
        if (diag && (nc * 16 + lr > wave * 16 + quad * 4 + r)) s = -1e30f;
        sacc[nc][r] = s;
        tmax[r] = fmaxf(tmax[r], s);
      }
#pragma unroll
    for (int r = 0; r < 4; r++) {
      tmax[r] = fmaxf(tmax[r], __shfl_xor(tmax[r], 1));
      tmax[r] = fmaxf(tmax[r], __shfl_xor(tmax[r], 2));
      tmax[r] = fmaxf(tmax[r], __shfl_xor(tmax[r], 4));
      tmax[r] = fmaxf(tmax[r], __shfl_xor(tmax[r], 8));
    }
    float alpha[4], psum[4];
#pragma unroll
    for (int r = 0; r < 4; r++) {
      float mn = fmaxf(m[r], tmax[r]);
      alpha[r] = __expf(m[r] - mn);
      m[r] = mn;
      psum[r] = 0.f;
    }
    // P stores: fragment-linear layout for the PV A-operand read
#pragma unroll
    for (int nc = 0; nc < 4; nc++)
#pragma unroll
      for (int r = 0; r < 4; r++) {
        float p = __expf(sacc[nc][r] - m[r]);
        psum[r] += p;
        int col = nc * 16 + lr;
        ldsP[wave * 1024 + (col >> 5) * 512 +
             (((col >> 3) & 3) * 16 + quad * 4 + r) * 8 + (col & 7)] = f2bf_bits(p);
      }
#pragma unroll
    for (int r = 0; r < 4; r++) {
      psum[r] += __shfl_xor(psum[r], 1);
      psum[r] += __shfl_xor(psum[r], 2);
      psum[r] += __shfl_xor(psum[r], 4);
      psum[r] += __shfl_xor(psum[r], 8);
      l[r] = l[r] * alpha[r] + psum[r];
    }
#pragma unroll
    for (int dc = 0; dc < 5; dc++)
#pragma unroll
      for (int r = 0; r < 4; r++) oacc[dc][r] *= alpha[r];
    __builtin_amdgcn_sched_barrier(0);
    // ---- O += P V (wave-local P, in-order DS within wave) ----
    bf16x8 pfrag[2];
#pragma unroll
    for (int kc = 0; kc < 2; kc++)
      pfrag[kc] = *(const bf16x8*)&ldsP[wave * 1024 + kc * 512 + lane * 8];
#pragma unroll
    for (int dc = 0; dc < 5; dc++)
#pragma unroll
      for (int kc = 0; kc < 2; kc++) {
        bf16x8 vf = *(const bf16x8*)&ldsVt[dc * 16 + lr][kc * 32 + quad * 8];
        oacc[dc] = __builtin_amdgcn_mfma_f32_16x16x32_bf16(pfrag[kc], vf, oacc[dc], 0, 0, 0);
      }
  }  // kt

  // ---- epilogue ----
#pragma unroll
  for (int dc = 0; dc < 5; dc++) {
    int d = dc * 16 + lr;
    if (d < DKH) {
#pragma unroll
      for (int r = 0; r < 4; r++) {
        int row = qt * 64 + wave * 16 + quad * 4 + r;
        float val = oacc[dc][r] / l[r];
        a[(size_t)(b * S_LEN + row) * CDIM + h * DKH + d] = __float2bfloat16(val);
      }
    }
  }
}

// ---------------- launch ----------------
extern "C" void kernel_launch(void* const* d_in, const int* in_sizes, int n_in,
                              void* d_out, int out_size, void* d_ws, size_t ws_size,
                              hipStream_t stream) {
  const float* x    = (const float*)d_in[0];
  const float* pos0 = (const float*)d_in[1];
  const float* pos1 = (const float*)d_in[2];
  const float* pos2 = (const float*)d_in[3];
  const float* ln1g = (const float*)d_in[4];
  const float* ln1b = (const float*)d_in[5];
  const float* wq   = (const float*)d_in[6];
  const float* wk   = (const float*)d_in[7];
  const float* wv   = (const float*)d_in[8];
  const float* wo   = (const float*)d_in[9];
  const float* wob  = (const float*)d_in[10];
  const float* ln2g = (const float*)d_in[11];
  const float* ln2b = (const float*)d_in[12];
  const float* w1   = (const float*)d_in[13];
  const float* b1   = (const float*)d_in[14];
  const float* w2   = (const float*)d_in[15];
  const float* b2   = (const float*)d_in[16];

  char* ws = (char*)d_ws;
  size_t off = 0;
  auto alloc = [&](size_t bytes) {
    char* p = ws + off;
    off += (bytes + 255) & ~(size_t)255;
    return p;
  };
  const size_t sz_qkvT = (size_t)4 * QKVNP * CDIM * sizeof(bf16);
  const size_t sz_woT  = (size_t)4 * CPAD * CDIM * sizeof(bf16);
  const size_t sz_w1T  = (size_t)4 * FFDIM * CDIM * sizeof(bf16);
  const size_t sz_w2T  = (size_t)4 * CPAD * FFDIM * sizeof(bf16);
  bf16* wqkvT = (bf16*)alloc(sz_qkvT);
  bf16* woT   = (bf16*)alloc(sz_woT);
  bf16* w1T   = (bf16*)alloc(sz_w1T);
  bf16* w2T   = (bf16*)alloc(sz_w2T);
  bf16* hbuf  = (bf16*)alloc((size_t)MROWS * CDIM * sizeof(bf16));
  bf16* abuf  = (bf16*)alloc((size_t)MROWS * CDIM * sizeof(bf16));
  bf16* ubuf  = (bf16*)alloc((size_t)MROWS * FFDIM * sizeof(bf16));
  bf16* qkvb  = (bf16*)alloc((size_t)MROWS * QKVN * sizeof(bf16));
  float* xf   = (float*)d_out;   // residual stream lives in d_out (fp32)

  // zero padded weight rows (re-done every launch; ws is re-poisoned)
  hipMemsetAsync(wqkvT, 0, sz_qkvT, stream);
  hipMemsetAsync(woT, 0, sz_woT, stream);
  hipMemsetAsync(w2T, 0, sz_w2T, stream);

  const size_t ils  = (size_t)CDIM * CDIM;       // fp32 per-layer in stride (C x C)
  const size_t ils2 = (size_t)CDIM * FFDIM;
  transpose_cvt<<<dim3(18, 18, 4), 256, 0, stream>>>(wq, wqkvT, CDIM, CDIM,
      ils, (size_t)QKVNP * CDIM);
  transpose_cvt<<<dim3(18, 18, 4), 256, 0, stream>>>(wk, wqkvT + (size_t)CDIM * CDIM, CDIM, CDIM,
      ils, (size_t)QKVNP * CDIM);
  transpose_cvt<<<dim3(18, 18, 4), 256, 0, stream>>>(wv, wqkvT + (size_t)2 * CDIM * CDIM, CDIM, CDIM,
      ils, (size_t)QKVNP * CDIM);
  transpose_cvt<<<dim3(18, 18, 4), 256, 0, stream>>>(wo, woT, CDIM, CDIM,
      ils, (size_t)CPAD * CDIM);
  transpose_cvt<<<dim3(72, 18, 4), 256, 0, stream>>>(w1, w1T, CDIM, FFDIM,
      ils2, (size_t)FFDIM * CDIM);
  transpose_cvt<<<dim3(18, 72, 4), 256, 0, stream>>>(w2, w2T, FFDIM, CDIM,
      ils2, (size_t)CPAD * FFDIM);

  build_xf<<<2304, 256, 0, stream>>>(x, pos0, pos1, pos2, xf);

  for (int l = 0; l < 4; l++) {
    bf16* wqkv_l = wqkvT + (size_t)l * QKVNP * CDIM;
    bf16* wo_l   = woT   + (size_t)l * CPAD * CDIM;
    bf16* w1_l   = w1T   + (size_t)l * FFDIM * CDIM;
    bf16* w2_l   = w2T   + (size_t)l * CPAD * FFDIM;

    ln_kernel<<<1024, 256, 0, stream>>>(xf, ln1g + l * CDIM, ln1b + l * CDIM, hbuf);
    // fused QKV: [4096,576] x [1792,576]^T -> qkvb [4096,1728]
    gemm2<128, false, false, 0, true><<<dim3(64, QKVNP / 128), 256, 0, stream>>>(
        hbuf, wqkv_l, nullptr, nullptr, qkvb, QKVN, QKVN, CDIM);
    attn_mfma<<<dim3(16, 32), 256, 0, stream>>>(qkvb, abuf);
    // proj + bias + residual -> xf (fp32)
    gemm2<64, true, true, 0, false><<<dim3(64, CPAD / 64), 256, 0, stream>>>(
        abuf, wo_l, wob + l * CDIM, xf, xf, CDIM, CDIM, CDIM);
    ln_kernel<<<1024, 256, 0, stream>>>(xf, ln2g + l * CDIM, ln2b + l * CDIM, hbuf);
    // FFN1 + bias + GeLU2 -> ubuf (bf16)
    gemm2<128, true, false, 1, true><<<dim3(64, FFDIM / 128), 256, 0, stream>>>(
        hbuf, w1_l, b1 + l * FFDIM, nullptr, ubuf, FFDIM, FFDIM, CDIM);
    // FFN2 + bias + residual -> xf (fp32)
    gemm2<64, true, true, 0, false><<<dim3(64, CPAD / 64), 256, 0, stream>>>(
        ubuf, w2_l, b2 + l * CDIM, xf, xf, CDIM, CDIM, FFDIM);
  }
}

// Round 7
// 805.321 us; speedup vs baseline: 1.1802x; 1.1802x over previous
//
#include <hip/hip_runtime.h>
#include <hip/hip_bf16.h>

typedef __hip_bfloat16 bf16;
using bf16x8 = __attribute__((ext_vector_type(8))) short;
using f32x4  = __attribute__((ext_vector_type(4))) float;

#define S_LEN 1024
#define CDIM  576
#define NHEAD 8
#define DKH   72
#define BATCH 4
#define MROWS 4096   // B*S
#define FFDIM 2304
#define QKVN  1728   // 3*C

// async global->LDS, 16B per lane, lane-ordered LDS destination
__device__ __forceinline__ void gload16(const void* g, void* l) {
  __builtin_amdgcn_global_load_lds(
      (const __attribute__((address_space(1))) unsigned int*)g,
      (__attribute__((address_space(3))) unsigned int*)l, 16, 0, 0);
}

// float -> bf16 bits (RNE), pure integer math (type-safe for LDS punning)
__device__ __forceinline__ short f2bf_bits(float x) {
  unsigned int u = __float_as_uint(x);
  u += 0x7fffu + ((u >> 16) & 1u);
  return (short)(u >> 16);
}

// ---------------- weight transpose + fp32->bf16 convert ----------------
// in: per-layer [K,N] fp32 (layer stride in_ls) -> out: [N,K] bf16 (layer stride out_ls)
__global__ __launch_bounds__(256) void transpose_cvt(
    const float* __restrict__ in, bf16* __restrict__ out, int K, int N,
    size_t in_ls, size_t out_ls) {
  __shared__ float tile[32][33];
  const float* inl = in + (size_t)blockIdx.z * in_ls;
  bf16* outl = out + (size_t)blockIdx.z * out_ls;
  int n0 = blockIdx.x * 32, k0 = blockIdx.y * 32;
  int tx = threadIdx.x & 31, ty = threadIdx.x >> 5;   // ty 0..7
#pragma unroll
  for (int i = 0; i < 32; i += 8)
    tile[ty + i][tx] = inl[(size_t)(k0 + ty + i) * N + (n0 + tx)];
  __syncthreads();
#pragma unroll
  for (int i = 0; i < 32; i += 8)
    outl[(size_t)(n0 + ty + i) * K + (k0 + tx)] = __float2bfloat16(tile[tx][ty + i]);
}

// ---------------- xf = right_shift(x) + pos ----------------
__global__ __launch_bounds__(256) void build_xf(
    const float* __restrict__ x, const float* __restrict__ p0,
    const float* __restrict__ p1, const float* __restrict__ p2,
    float* __restrict__ xf) {
  int idx = blockIdx.x * 256 + threadIdx.x;      // one float4 per thread
  int c4 = idx % 144;
  int s  = (idx / 144) & (S_LEN - 1);
  int b  = idx / (144 * S_LEN);
  int c  = c4 * 4;
  int t = s >> 8, hh = (s >> 4) & 15, w = s & 15;
  float4 pv;
  if (c < 192)       pv = *(const float4*)&p0[t  * 192 + c];
  else if (c < 384)  pv = *(const float4*)&p1[hh * 192 + c - 192];
  else               pv = *(const float4*)&p2[w  * 192 + c - 384];
  float4 xv = make_float4(0.f, 0.f, 0.f, 0.f);
  if (s > 0) xv = *(const float4*)&x[((size_t)b * S_LEN + s - 1) * CDIM + c];
  float4 r = make_float4(xv.x + pv.x, xv.y + pv.y, xv.z + pv.z, xv.w + pv.w);
  *(float4*)&xf[((size_t)b * S_LEN + s) * CDIM + c] = r;
}

// ---------------- LayerNorm (eps added to rsqrt, per reference) ----------------
__global__ __launch_bounds__(256) void ln_kernel(
    const float* __restrict__ x, const float* __restrict__ g,
    const float* __restrict__ b, bf16* __restrict__ out) {
  int row  = blockIdx.x * 4 + (threadIdx.x >> 6);
  int lane = threadIdx.x & 63;
  const float* xr = x + (size_t)row * CDIM;
  float vals[9];
  float sum = 0.f;
#pragma unroll
  for (int i = 0; i < 9; i++) { vals[i] = xr[lane + 64 * i]; sum += vals[i]; }
#pragma unroll
  for (int o = 1; o < 64; o <<= 1) sum += __shfl_xor(sum, o);
  float mu = sum * (1.f / CDIM);
  float vs = 0.f;
#pragma unroll
  for (int i = 0; i < 9; i++) { float d = vals[i] - mu; vs += d * d; }
#pragma unroll
  for (int o = 1; o < 64; o <<= 1) vs += __shfl_xor(vs, o);
  float mult = 1e-5f + rsqrtf(vs * (1.f / CDIM));
  bf16* orow = out + (size_t)row * CDIM;
#pragma unroll
  for (int i = 0; i < 9; i++) {
    int c = lane + 64 * i;
    orow[c] = __float2bfloat16((vals[i] - mu) * mult * g[c] + b[c]);
  }
}

// ---------------- GEMM v3: VGPR staging (compiler-pipelined), BN=64 ----------------
// out[M,N] = act(A[M,K] @ Bt[N,K]^T + bias) (+ res)
// BM=128: waves 2x2, each 4m x 2n frags (8 MFMA / BK=32). BM=64: v1 (2m x 2n).
// LDS leading stride 44 shorts (22 dwords): all LDS ops <=2-way bank alias (free).
template <int BM, bool BIAS, bool RES, int ACT, bool OUTBF>
__global__ __launch_bounds__(256) void gemm3(
    const bf16* __restrict__ A, const bf16* __restrict__ Bt,
    const float* __restrict__ bias, const float* __restrict__ res,
    void* __restrict__ outp, int N, int K) {
  constexpr int MI = BM / 32;
  __shared__ short ldsA[BM][44];
  __shared__ short ldsB[64][44];
  const int tid = threadIdx.x, lane = tid & 63, wave = tid >> 6;
  const int lr = lane & 15, quad = lane >> 4;
  const int m0 = blockIdx.x * BM, n0 = blockIdx.y * 64;
  const int wm = (wave & 1) * (BM / 2), wn = (wave >> 1) * 32;
  f32x4 acc[MI][2] = {};
  const int arow = (BM == 128) ? (tid >> 1) : (tid >> 2);
  const int acol = (BM == 128) ? ((tid & 1) * 16) : ((tid & 3) * 8);
  const int brow = tid >> 2, bcol = (tid & 3) * 8;
  const short* Ag = (const short*)A  + (size_t)(m0 + arow) * K + acol;
  const short* Bg = (const short*)Bt + (size_t)(n0 + brow) * K + bcol;

  for (int k0 = 0; k0 < K; k0 += 32) {
    bf16x8 av0 = *(const bf16x8*)(Ag + k0);
    bf16x8 av1;
    if (BM == 128) av1 = *(const bf16x8*)(Ag + k0 + 8);
    bf16x8 bv = *(const bf16x8*)(Bg + k0);
    *(bf16x8*)&ldsA[arow][acol] = av0;
    if (BM == 128) *(bf16x8*)&ldsA[arow][acol + 8] = av1;
    *(bf16x8*)&ldsB[brow][bcol] = bv;
    __syncthreads();
    bf16x8 af[MI], bfv[2];
#pragma unroll
    for (int mi = 0; mi < MI; mi++)
      af[mi] = *(const bf16x8*)&ldsA[wm + mi * 16 + lr][quad * 8];
#pragma unroll
    for (int ni = 0; ni < 2; ni++)
      bfv[ni] = *(const bf16x8*)&ldsB[wn + ni * 16 + lr][quad * 8];
#pragma unroll
    for (int mi = 0; mi < MI; mi++)
#pragma unroll
      for (int ni = 0; ni < 2; ni++)
        acc[mi][ni] = __builtin_amdgcn_mfma_f32_16x16x32_bf16(af[mi], bfv[ni], acc[mi][ni], 0, 0, 0);
    __syncthreads();
  }

  float* fout = (float*)outp;
  bf16*  bout = (bf16*)outp;
#pragma unroll
  for (int mi = 0; mi < MI; mi++)
#pragma unroll
    for (int ni = 0; ni < 2; ni++) {
      int col = n0 + wn + ni * 16 + lr;
#pragma unroll
      for (int r = 0; r < 4; r++) {
        int row = m0 + wm + mi * 16 + quad * 4 + r;
        float v = acc[mi][ni][r];
        if (BIAS) v += bias[col];
        if (ACT == 1) v = v / (1.f + __expf(-1.702f * v));   // GeLU2
        size_t idx = (size_t)row * N + col;
        if (RES) v += res[idx];
        if (OUTBF) bout[idx] = __float2bfloat16(v);
        else       fout[idx] = v;
      }
    }
}

// ---------------- MFMA flash attention v2 (unchanged from round 6) ----------------
__global__ __launch_bounds__(256) void attn_mfma(
    const bf16* __restrict__ qkv, bf16* __restrict__ a) {
  __shared__ short ldsK[12 * 512];     // page (nc*3+c), lane-linear
  __shared__ short ldsVt[80][104];     // [d][key], padded rows
  __shared__ short ldsP[4 * 1024];     // per-wave, fragment-linear (2 kc pages)
  const int bh = blockIdx.y, b = bh >> 3, h = bh & 7;
  const int tid = threadIdx.x, wave = tid >> 6, lane = tid & 63;
  const int lr = lane & 15, quad = lane >> 4;
  const int qt = 15 - (int)blockIdx.x;
  const float scale = 0.11785113019775793f;  // 1/sqrt(72)
  const int qcol = h * DKH, kcol = CDIM + h * DKH, vcol = 2 * CDIM + h * DKH;

  const int qrow = qt * 64 + wave * 16 + lr;
  const short* qg = (const short*)qkv + (size_t)(b * S_LEN + qrow) * QKVN + qcol;
  bf16x8 qfrag[3];
#pragma unroll
  for (int c = 0; c < 3; c++) {
    int d0 = c * 32 + quad * 8;
    bf16x8 z = {0, 0, 0, 0, 0, 0, 0, 0};
    qfrag[c] = (d0 < DKH) ? *(const bf16x8*)(qg + d0) : z;
  }
  f32x4 oacc[5] = {};
  float m[4], l[4];
#pragma unroll
  for (int r = 0; r < 4; r++) { m[r] = -1e30f; l[r] = 0.f; }

  for (int kt = 0; kt <= qt; kt++) {
    __syncthreads();
    {
      const short* kg = (const short*)qkv +
          (size_t)(b * S_LEN + kt * 64 + wave * 16 + lr) * QKVN + kcol + quad * 8;
#pragma unroll
      for (int c = 0; c < 3; c++)
        gload16(kg + c * 32, &ldsK[(wave * 3 + c) * 512]);
    }
    {
      int key = tid & 63, dgb = tid >> 6;
      const short* vg = (const short*)qkv + (size_t)(b * S_LEN + kt * 64 + key) * QKVN + vcol;
#pragma unroll
      for (int pass = 0; pass < 3; pass++) {
        int d0 = (dgb + pass * 4) * 8;  // 0..88
        if (d0 < 80) {
          bf16x8 vv = {0, 0, 0, 0, 0, 0, 0, 0};
          if (d0 < DKH) vv = *(const bf16x8*)(vg + d0);
#pragma unroll
          for (int j = 0; j < 8; j++) ldsVt[d0 + j][key] = vv[j];
        }
      }
    }
    __syncthreads();
    f32x4 sacc[4] = {};
#pragma unroll
    for (int nc = 0; nc < 4; nc++)
#pragma unroll
      for (int c = 0; c < 3; c++) {
        bf16x8 kf = *(const bf16x8*)&ldsK[(nc * 3 + c) * 512 + lane * 8];
        sacc[nc] = __builtin_amdgcn_mfma_f32_16x16x32_bf16(qfrag[c], kf, sacc[nc], 0, 0, 0);
      }
    float tmax[4];
#pragma unroll
    for (int r = 0; r < 4; r++) tmax[r] = -1e30f;
    bool diag = (kt == qt);
#pragma unroll
    for (int nc = 0; nc < 4; nc++)
#pragma unroll
      for (int r = 0; r < 4; r++) {
        float s = sacc[nc][r] * scale;
        if (diag && (nc * 16 + lr > wave * 16 + quad * 4 + r)) s = -1e30f;
        sacc[nc][r] = s;
        tmax[r] = fmaxf(tmax[r], s);
      }
#pragma unroll
    for (int r = 0; r < 4; r++) {
      tmax[r] = fmaxf(tmax[r], __shfl_xor(tmax[r], 1));
      tmax[r] = fmaxf(tmax[r], __shfl_xor(tmax[r], 2));
      tmax[r] = fmaxf(tmax[r], __shfl_xor(tmax[r], 4));
      tmax[r] = fmaxf(tmax[r], __shfl_xor(tmax[r], 8));
    }
    float alpha[4], psum[4];
#pragma unroll
    for (int r = 0; r < 4; r++) {
      float mn = fmaxf(m[r], tmax[r]);
      alpha[r] = __expf(m[r] - mn);
      m[r] = mn;
      psum[r] = 0.f;
    }
#pragma unroll
    for (int nc = 0; nc < 4; nc++)
#pragma unroll
      for (int r = 0; r < 4; r++) {
        float p = __expf(sacc[nc][r] - m[r]);
        psum[r] += p;
        int col = nc * 16 + lr;
        ldsP[wave * 1024 + (col >> 5) * 512 +
             (((col >> 3) & 3) * 16 + quad * 4 + r) * 8 + (col & 7)] = f2bf_bits(p);
      }
#pragma unroll
    for (int r = 0; r < 4; r++) {
      psum[r] += __shfl_xor(psum[r], 1);
      psum[r] += __shfl_xor(psum[r], 2);
      psum[r] += __shfl_xor(psum[r], 4);
      psum[r] += __shfl_xor(psum[r], 8);
      l[r] = l[r] * alpha[r] + psum[r];
    }
#pragma unroll
    for (int dc = 0; dc < 5; dc++)
#pragma unroll
      for (int r = 0; r < 4; r++) oacc[dc][r] *= alpha[r];
    __builtin_amdgcn_sched_barrier(0);
    bf16x8 pfrag[2];
#pragma unroll
    for (int kc = 0; kc < 2; kc++)
      pfrag[kc] = *(const bf16x8*)&ldsP[wave * 1024 + kc * 512 + lane * 8];
#pragma unroll
    for (int dc = 0; dc < 5; dc++)
#pragma unroll
      for (int kc = 0; kc < 2; kc++) {
        bf16x8 vf = *(const bf16x8*)&ldsVt[dc * 16 + lr][kc * 32 + quad * 8];
        oacc[dc] = __builtin_amdgcn_mfma_f32_16x16x32_bf16(pfrag[kc], vf, oacc[dc], 0, 0, 0);
      }
  }  // kt

#pragma unroll
  for (int dc = 0; dc < 5; dc++) {
    int d = dc * 16 + lr;
    if (d < DKH) {
#pragma unroll
      for (int r = 0; r < 4; r++) {
        int row = qt * 64 + wave * 16 + quad * 4 + r;
        float val = oacc[dc][r] / l[r];
        a[(size_t)(b * S_LEN + row) * CDIM + h * DKH + d] = __float2bfloat16(val);
      }
    }
  }
}

// ---------------- launch ----------------
extern "C" void kernel_launch(void* const* d_in, const int* in_sizes, int n_in,
                              void* d_out, int out_size, void* d_ws, size_t ws_size,
                              hipStream_t stream) {
  const float* x    = (const float*)d_in[0];
  const float* pos0 = (const float*)d_in[1];
  const float* pos1 = (const float*)d_in[2];
  const float* pos2 = (const float*)d_in[3];
  const float* ln1g = (const float*)d_in[4];
  const float* ln1b = (const float*)d_in[5];
  const float* wq   = (const float*)d_in[6];
  const float* wk   = (const float*)d_in[7];
  const float* wv   = (const float*)d_in[8];
  const float* wo   = (const float*)d_in[9];
  const float* wob  = (const float*)d_in[10];
  const float* ln2g = (const float*)d_in[11];
  const float* ln2b = (const float*)d_in[12];
  const float* w1   = (const float*)d_in[13];
  const float* b1   = (const float*)d_in[14];
  const float* w2   = (const float*)d_in[15];
  const float* b2   = (const float*)d_in[16];

  char* ws = (char*)d_ws;
  size_t off = 0;
  auto alloc = [&](size_t bytes) {
    char* p = ws + off;
    off += (bytes + 255) & ~(size_t)255;
    return p;
  };
  bf16* wqkvT = (bf16*)alloc((size_t)4 * QKVN * CDIM * sizeof(bf16));
  bf16* woT   = (bf16*)alloc((size_t)4 * CDIM * CDIM * sizeof(bf16));
  bf16* w1T   = (bf16*)alloc((size_t)4 * FFDIM * CDIM * sizeof(bf16));
  bf16* w2T   = (bf16*)alloc((size_t)4 * CDIM * FFDIM * sizeof(bf16));
  bf16* hbuf  = (bf16*)alloc((size_t)MROWS * CDIM * sizeof(bf16));
  bf16* abuf  = (bf16*)alloc((size_t)MROWS * CDIM * sizeof(bf16));
  bf16* ubuf  = (bf16*)alloc((size_t)MROWS * FFDIM * sizeof(bf16));
  bf16* qkvb  = (bf16*)alloc((size_t)MROWS * QKVN * sizeof(bf16));
  float* xf   = (float*)d_out;   // residual stream lives in d_out (fp32)

  const size_t ils  = (size_t)CDIM * CDIM;
  const size_t ils2 = (size_t)CDIM * FFDIM;
  const size_t qkv_ls = (size_t)QKVN * CDIM;
  transpose_cvt<<<dim3(18, 18, 4), 256, 0, stream>>>(wq, wqkvT, CDIM, CDIM, ils, qkv_ls);
  transpose_cvt<<<dim3(18, 18, 4), 256, 0, stream>>>(wk, wqkvT + (size_t)CDIM * CDIM, CDIM, CDIM, ils, qkv_ls);
  transpose_cvt<<<dim3(18, 18, 4), 256, 0, stream>>>(wv, wqkvT + (size_t)2 * CDIM * CDIM, CDIM, CDIM, ils, qkv_ls);
  transpose_cvt<<<dim3(18, 18, 4), 256, 0, stream>>>(wo, woT, CDIM, CDIM, ils, ils);
  transpose_cvt<<<dim3(72, 18, 4), 256, 0, stream>>>(w1, w1T, CDIM, FFDIM, ils2, ils2);
  transpose_cvt<<<dim3(18, 72, 4), 256, 0, stream>>>(w2, w2T, FFDIM, CDIM, ils2, ils2);

  build_xf<<<2304, 256, 0, stream>>>(x, pos0, pos1, pos2, xf);

  for (int l = 0; l < 4; l++) {
    bf16* wqkv_l = wqkvT + (size_t)l * qkv_ls;
    bf16* wo_l   = woT   + (size_t)l * ils;
    bf16* w1_l   = w1T   + (size_t)l * ils2;
    bf16* w2_l   = w2T   + (size_t)l * ils2;

    ln_kernel<<<1024, 256, 0, stream>>>(xf, ln1g + l * CDIM, ln1b + l * CDIM, hbuf);
    // fused QKV: [4096,576] x [1728,576]^T -> qkvb (BM=128, 864 blocks)
    gemm3<128, false, false, 0, true><<<dim3(32, QKVN / 64), 256, 0, stream>>>(
        hbuf, wqkv_l, nullptr, nullptr, qkvb, QKVN, CDIM);
    attn_mfma<<<dim3(16, 32), 256, 0, stream>>>(qkvb, abuf);
    // proj + bias + residual -> xf (BM=64, 576 blocks)
    gemm3<64, true, true, 0, false><<<dim3(64, CDIM / 64), 256, 0, stream>>>(
        abuf, wo_l, wob + l * CDIM, xf, xf, CDIM, CDIM);
    ln_kernel<<<1024, 256, 0, stream>>>(xf, ln2g + l * CDIM, ln2b + l * CDIM, hbuf);
    // FFN1 + bias + GeLU2 -> ubuf (BM=128, 1152 blocks)
    gemm3<128, true, false, 1, true><<<dim3(32, FFDIM / 64), 256, 0, stream>>>(
        hbuf, w1_l, b1 + l * FFDIM, nullptr, ubuf, FFDIM, CDIM);
    // FFN2 + bias + residual -> xf (BM=64, 576 blocks)
    gemm3<64, true, true, 0, false><<<dim3(64, CDIM / 64), 256, 0, stream>>>(
        ubuf, w2_l, b2 + l * CDIM, xf, xf, CDIM, FFDIM);
  }
}